// Round 12
// baseline (3724.792 us; speedup 1.0000x reference)
//
#include <hip/hip_runtime.h>
#include <hip/hip_bf16.h>
#include <cstddef>
#include <cstdint>

#define NN   2048
#define BB   32
#define TT   24
#define CIN  2
#define HH   64
#define EMBD 16
#define HOR  12
#define XC   (TT*BB*CIN)   // 1536 cols of precomputed A@x
#define PW   4096          // P row width: cols [0,2048)=P2, [2048,4096)=P1
#define NT2  64            // K-tiles of 32 (K=2048)
#define HOFF ((size_t)2048*NN)   // h1 row offset in Bhi/Blo

using bfrag  = __attribute__((ext_vector_type(8))) short;   // 8 bf16 = 4 VGPR
using f32x4  = __attribute__((ext_vector_type(4))) float;
using f32x16 = __attribute__((ext_vector_type(16))) float;

static __device__ __forceinline__ short f2bf(float f) {
    __hip_bfloat16 h = __float2bfloat16(f);
    return *reinterpret_cast<short*>(&h);
}
static __device__ __forceinline__ float bf2f(short s) {
    __hip_bfloat16 h;
    *reinterpret_cast<short*>(&h) = s;
    return __bfloat162float(h);
}
static __device__ __forceinline__ unsigned int packsplit(float v) {
    short hb = f2bf(v);
    short lb = f2bf(v - bf2f(hb));
    return (unsigned int)(unsigned short)hb | ((unsigned int)(unsigned short)lb << 16);
}
// fast transcendentals: v_exp_f32 + v_rcp_f32; saturate correctly, no NaN
static __device__ __forceinline__ float fsig(float x) {
    return __builtin_amdgcn_rcpf(1.f + __expf(-x));
}
static __device__ __forceinline__ float ftanh(float x) {
    return 1.f - 2.f*__builtin_amdgcn_rcpf(1.f + __expf(2.f*x));
}

#define AS1 __attribute__((address_space(1)))
#define AS3 __attribute__((address_space(3)))
static __device__ __forceinline__ void gload16(const short* g, short* l) {
    __builtin_amdgcn_global_load_lds((const AS1 void*)g, (AS3 void*)l, 16, 0, 0);
}

// ---------- A = softmax(relu(E E^T)) -> split bf16 hi/lo ----------
__global__ __launch_bounds__(256) void compute_A_kernel(const float* __restrict__ E,
                                                        short* __restrict__ Ahi,
                                                        short* __restrict__ Alo) {
    __shared__ float srow[NN];
    __shared__ float sred[256];
    int row = blockIdx.x;
    float er[EMBD];
#pragma unroll
    for (int k = 0; k < EMBD; ++k) er[k] = E[row*EMBD + k];
    float lmax = -1e30f;
    for (int j = threadIdx.x; j < NN; j += 256) {
        const float* ej = E + j*EMBD;
        float d = 0.f;
#pragma unroll
        for (int k = 0; k < EMBD; ++k) d = fmaf(er[k], ej[k], d);
        d = fmaxf(d, 0.f);
        srow[j] = d;
        lmax = fmaxf(lmax, d);
    }
    sred[threadIdx.x] = lmax;
    __syncthreads();
    for (int s = 128; s > 0; s >>= 1) {
        if (threadIdx.x < s) sred[threadIdx.x] = fmaxf(sred[threadIdx.x], sred[threadIdx.x+s]);
        __syncthreads();
    }
    float rmax = sred[0];
    __syncthreads();
    float lsum = 0.f;
    for (int j = threadIdx.x; j < NN; j += 256) {
        float e = expf(srow[j] - rmax);
        srow[j] = e;
        lsum += e;
    }
    sred[threadIdx.x] = lsum;
    __syncthreads();
    for (int s = 128; s > 0; s >>= 1) {
        if (threadIdx.x < s) sred[threadIdx.x] += sred[threadIdx.x+s];
        __syncthreads();
    }
    float rinv = 1.f / sred[0];
    for (int j = threadIdx.x; j < NN; j += 256) {
        float v = srow[j] * rinv;
        short h = f2bf(v);
        Ahi[(size_t)row*NN + j] = h;
        Alo[(size_t)row*NN + j] = f2bf(v - bf2f(h));
    }
}

// ---------------- build XallT hi/lo: [col=(t*32+b)*2+c][n] ----------------
__global__ void scatter_xall(const float* __restrict__ x,
                             short* __restrict__ hi, short* __restrict__ lo) {
    int idx = blockIdx.x*256 + threadIdx.x;     // col*2048 + n
    int n = idx & (NN-1);
    int col = idx >> 11;
    int c = col & 1, b = (col >> 1) & 31, t = col >> 6;
    float v = x[(size_t)(((size_t)b*TT + t)*NN + n)*CIN + c];
    short h = f2bf(v);
    size_t o = (size_t)col*NN + n;
    hi[o] = h;
    lo[o] = f2bf(v - bf2f(h));
}

// ---------------- W^T split: Wt[j][c] = split(W[rowoff+c][j]) ----------------
__global__ void wsplit_T(const float* __restrict__ W, int rowoff, int Kd,
                         short* __restrict__ hi, short* __restrict__ lo) {
    int id = blockIdx.x*256 + threadIdx.x;      // j*Kd + c
    if (id >= 256*Kd) return;
    int j = id / Kd, c = id - j*Kd;
    float v = W[(size_t)(rowoff + c)*256 + j];
    short h = f2bf(v);
    hi[id] = h;
    lo[id] = f2bf(v - bf2f(h));
}

// ---------------- convX GEMM: f32 out (proven kernel) --------------
__global__ __launch_bounds__(256, 3) void gc3_gemm(
        const short* __restrict__ Ahi, const short* __restrict__ Alo,
        const short* __restrict__ Bhi, const short* __restrict__ Blo,
        float* __restrict__ Cout, int outStride) {
    __shared__ short As[12288];
    short* AsHi = As;
    short* AsLo = As + 2048;
    short* BsHi = As + 4096;
    short* BsLo = As + 8192;
    const int t = threadIdx.x;
    const int w = t >> 6, lane = t & 63;
    const int wm = w >> 1, wn = w & 1;
    const int fr = lane & 15, fc = lane >> 4;
    const int rowbase = blockIdx.y * 64;
    const int colbase = blockIdx.x * 128;

    const int rp = t >> 3, ql = t & 7;
    const int qs = ql ^ (rp & 7);
    const int srow = rp*2 + (qs >> 2);
    const int sch  = (qs & 3) * 8;
    const short* aHiS = Ahi + (size_t)(rowbase + srow)*NN + sch;
    const short* aLoS = Alo + (size_t)(rowbase + srow)*NN + sch;
    const short* bHiS = Bhi + (size_t)(colbase + srow)*NN + sch;
    const short* bLoS = Blo + (size_t)(colbase + srow)*NN + sch;
    const size_t bHalf = (size_t)64*NN;

    short* aHiD  = AsHi + t*8;
    short* aLoD  = AsLo + t*8;
    short* bHiD0 = BsHi + t*8;
    short* bHiD1 = BsHi + 2048 + t*8;
    short* bLoD0 = BsLo + t*8;
    short* bLoD1 = BsLo + 2048 + t*8;

    auto ldsoff0 = [](int row, int f) {
        int rr = row >> 1;
        int q = (((row & 1) << 2) | f) ^ (rr & 7);
        return rr*64 + q*8;
    };
    int aoff[2], boff[4];
#pragma unroll
    for (int m = 0; m < 2; ++m) aoff[m] = ldsoff0(wm*32 + m*16 + fr, fc);
#pragma unroll
    for (int n = 0; n < 4; ++n) boff[n] = ldsoff0(wn*64 + n*16 + fr, fc);

    f32x4 acc[2][4];
#pragma unroll
    for (int m = 0; m < 2; ++m)
#pragma unroll
        for (int n = 0; n < 4; ++n)
#pragma unroll
            for (int r = 0; r < 4; ++r) acc[m][n][r] = 0.f;

    for (int k0 = 0; k0 < NN; k0 += 32) {
        gload16(aHiS, aHiD);
        gload16(aLoS, aLoD);
        gload16(bHiS, bHiD0);
        gload16(bHiS + bHalf, bHiD1);
        gload16(bLoS, bLoD0);
        gload16(bLoS + bHalf, bLoD1);
        aHiS += 32; aLoS += 32; bHiS += 32; bLoS += 32;
        __syncthreads();
        bfrag ah[2], al[2], bh[4], bl[4];
#pragma unroll
        for (int m = 0; m < 2; ++m) {
            ah[m] = *(const bfrag*)(AsHi + aoff[m]);
            al[m] = *(const bfrag*)(AsLo + aoff[m]);
        }
#pragma unroll
        for (int n = 0; n < 4; ++n) {
            bh[n] = *(const bfrag*)(BsHi + boff[n]);
            bl[n] = *(const bfrag*)(BsLo + boff[n]);
        }
#pragma unroll
        for (int m = 0; m < 2; ++m)
#pragma unroll
            for (int n = 0; n < 4; ++n) {
                acc[m][n] = __builtin_amdgcn_mfma_f32_16x16x32_bf16(ah[m], bh[n], acc[m][n], 0, 0, 0);
                acc[m][n] = __builtin_amdgcn_mfma_f32_16x16x32_bf16(ah[m], bl[n], acc[m][n], 0, 0, 0);
                acc[m][n] = __builtin_amdgcn_mfma_f32_16x16x32_bf16(al[m], bh[n], acc[m][n], 0, 0, 0);
            }
        __syncthreads();
    }
#pragma unroll
    for (int m = 0; m < 2; ++m) {
        const int gr = rowbase + wm*32 + m*16 + fc*4;
#pragma unroll
        for (int n = 0; n < 4; ++n) {
            const int gc = colbase + wn*64 + n*16 + fr;
#pragma unroll
            for (int r = 0; r < 4; ++r)
                Cout[(size_t)(gr + r)*outStride + gc] = acc[m][n][r];
        }
    }
}

// ------- recurrent GEMM: split 3-term, K=2048, BK=32, 32x32x16 frags ---------
// C[2048][PW] packed = (Ah+Al) @ (Bh+Bl)^T (3 terms, Al*Bl dropped)
// 128x256 tile, 8 waves (2Mx4N), 3-deep LDS (144KB), vmcnt(6) counted, 1 barrier.
// LDS layout: 128-BYTE ROWS with hi/lo interleaved -- As[128][64 shorts]:
// chunks 0-3 = hi (BK=32), chunks 4-7 = lo; Bs[256][64]. This restores the
// gemm8p-proven geometry (128B rows, chunk ^= row&7) that measured 0 bank
// conflicts; 64B-row variants measured a structural 4cy/read regardless of
// swizzle (rounds 9-11).
__global__ __launch_bounds__(512, 2) void gcsplit(
        const short* __restrict__ Ahi, const short* __restrict__ Alo,
        const short* __restrict__ Bhi, const short* __restrict__ Blo,
        unsigned int* __restrict__ Cpk, int colstart) {
    __shared__ short lds[3*24576];
    const int tid = threadIdx.x;
    const int w = tid >> 6, lane = tid & 63;
    const int wm = w >> 2, wn = w & 3;
    const int lr = lane & 31, lh = lane >> 5;
    // bijective XCD swizzle (grid counts divisible by 8)
    const int gx = gridDim.x;
    const int nwg = gx * gridDim.y;
    const int fid = blockIdx.y * gx + blockIdx.x;
    const int swz = (fid & 7) * (nwg >> 3) + (fid >> 3);
    const int rowbase = (swz / gx) * 128;
    const int colbase = colstart + (swz % gx) * 256;

    // staging decode: thread -> (row = s*64 + tid>>3, c' = tid&7),
    // source chunk c = c' ^ (row&7); c<4 -> hi plane col c, else lo plane col c-4.
    // 64 = 0 mod 8 so (row&7) = (tid>>3)&7 for every sweep -> one decode.
    const int trow = tid >> 3;
    const int ca = (tid & 7) ^ (trow & 7);
    const short* aplane = (ca < 4) ? Ahi : Alo;
    const short* bplane = (ca < 4) ? Bhi : Blo;
    const int ccol = (ca & 3) * 8;
    const short* aS0 = aplane + (size_t)(rowbase + trow)*NN + ccol;
    const short* aS1 = aplane + (size_t)(rowbase + 64 + trow)*NN + ccol;
    const short* bS0 = bplane + (size_t)(colbase + trow)*NN + ccol;
    const short* bS1 = bplane + (size_t)(colbase + 64 + trow)*NN + ccol;
    const short* bS2 = bplane + (size_t)(colbase + 128 + trow)*NN + ccol;
    const short* bS3 = bplane + (size_t)(colbase + 192 + trow)*NN + ccol;

    // fragment read offsets (shorts): row*64 + (c ^ (row&7))*8, c in 0..7
    auto ldsoff = [](int row, int c) {
        return row*64 + (c ^ (row & 7))*8;
    };
    int aoffH[2][2], aoffL[2][2], boffH[2][2], boffL[2][2];
#pragma unroll
    for (int m = 0; m < 2; ++m)
#pragma unroll
        for (int ks = 0; ks < 2; ++ks) {
            int row = wm*64 + m*32 + lr;
            aoffH[m][ks] = ldsoff(row, ks*2 + lh);
            aoffL[m][ks] = ldsoff(row, 4 + ks*2 + lh);
        }
#pragma unroll
    for (int n = 0; n < 2; ++n)
#pragma unroll
        for (int ks = 0; ks < 2; ++ks) {
            int row = wn*64 + n*32 + lr;
            boffH[n][ks] = 8192 + ldsoff(row, ks*2 + lh);
            boffL[n][ks] = 8192 + ldsoff(row, 4 + ks*2 + lh);
        }

    f32x16 acc[2][2];
#pragma unroll
    for (int m = 0; m < 2; ++m)
#pragma unroll
        for (int n = 0; n < 2; ++n)
#pragma unroll
            for (int r = 0; r < 16; ++r) acc[m][n][r] = 0.f;

    short* bC = lds;             // compute buffer (tile t)
    short* bN = lds + 24576;     // tile t+1
    short* bP = lds + 49152;     // prefetch dest (tile t+2)

    auto STAGE = [&](short* dst, int koff) {
        gload16(aS0 + koff, dst + tid*8);
        gload16(aS1 + koff, dst + 4096  + tid*8);
        gload16(bS0 + koff, dst + 8192  + tid*8);
        gload16(bS1 + koff, dst + 12288 + tid*8);
        gload16(bS2 + koff, dst + 16384 + tid*8);
        gload16(bS3 + koff, dst + 20480 + tid*8);
    };
    // prologue: stage tiles 0 and 1
    STAGE(bC, 0);
    STAGE(bN, 32);

    for (int t = 0; t < NT2; ++t) {
        // wait: tile t's 6 loads done (tile t+1's 6 may remain in flight)
        if (t < NT2-1) { asm volatile("s_waitcnt vmcnt(6)" ::: "memory"); }
        else           { asm volatile("s_waitcnt vmcnt(0)" ::: "memory"); }
        __builtin_amdgcn_s_barrier();     // buf bC ready; bP free
        if (t + 2 < NT2) STAGE(bP, (t + 2) * 32);
        __builtin_amdgcn_sched_barrier(0);   // pin stage-issue before compute
        // issue ALL 16 reads first (hh operands first); fine-grained lgkmcnt
        // lets tail reads land under the first MFMA cluster
        bfrag ah[2][2], al[2][2], bh[2][2], bl[2][2];   // [ks][idx]
#pragma unroll
        for (int ks = 0; ks < 2; ++ks) {
#pragma unroll
            for (int m = 0; m < 2; ++m) ah[ks][m] = *(const bfrag*)(bC + aoffH[m][ks]);
#pragma unroll
            for (int n = 0; n < 2; ++n) bh[ks][n] = *(const bfrag*)(bC + boffH[n][ks]);
        }
#pragma unroll
        for (int ks = 0; ks < 2; ++ks) {
#pragma unroll
            for (int m = 0; m < 2; ++m) al[ks][m] = *(const bfrag*)(bC + aoffL[m][ks]);
#pragma unroll
            for (int n = 0; n < 2; ++n) bl[ks][n] = *(const bfrag*)(bC + boffL[n][ks]);
        }
        __builtin_amdgcn_s_setprio(1);
#pragma unroll
        for (int ks = 0; ks < 2; ++ks)
#pragma unroll
            for (int m = 0; m < 2; ++m)
#pragma unroll
                for (int n = 0; n < 2; ++n)
                    acc[m][n] = __builtin_amdgcn_mfma_f32_32x32x16_bf16(
                        ah[ks][m], bh[ks][n], acc[m][n], 0, 0, 0);
#pragma unroll
        for (int ks = 0; ks < 2; ++ks)
#pragma unroll
            for (int m = 0; m < 2; ++m)
#pragma unroll
                for (int n = 0; n < 2; ++n) {
                    acc[m][n] = __builtin_amdgcn_mfma_f32_32x32x16_bf16(
                        ah[ks][m], bl[ks][n], acc[m][n], 0, 0, 0);
                    acc[m][n] = __builtin_amdgcn_mfma_f32_32x32x16_bf16(
                        al[ks][m], bh[ks][n], acc[m][n], 0, 0, 0);
                }
        __builtin_amdgcn_s_setprio(0);
        // rotate buffers
        short* tmp = bC; bC = bN; bN = bP; bP = tmp;
    }
    // epilogue: C/D (32x32): col = lane&31, row = (r&3) + 8*(r>>2) + 4*(lane>>5)
#pragma unroll
    for (int m = 0; m < 2; ++m) {
        const int gr0 = rowbase + wm*64 + m*32 + 4*lh;
#pragma unroll
        for (int n = 0; n < 2; ++n) {
            const int gc = colbase + wn*64 + n*32 + lr;
#pragma unroll
            for (int r = 0; r < 16; ++r) {
                int gr = gr0 + (r & 3) + 8*(r >> 2);
                Cpk[(size_t)gr*PW + gc] = packsplit(acc[m][n][r]);
            }
        }
    }
}

// ---------------- MFMA LSTM cell body (shared device fn) ----------------
// P packed (hi|lo). h written to Bhi/Blo rows (b*64+k), stride NN.
template<int NCH, bool XEP>
static __device__ __forceinline__ void cell_body(
        const unsigned int* __restrict__ P,
        const float* __restrict__ convX,
        const float* __restrict__ Wx,
        const short* __restrict__ Wthi, const short* __restrict__ Wtlo,
        const float* __restrict__ bias,
        float* __restrict__ cbuf,
        short* __restrict__ bhi, short* __restrict__ blo,
        int tstep, int n0blk, int b) {
    const int t = threadIdx.x;
    const int w = t >> 6, lane = t & 63;
    const int fr = lane & 15, fc = lane >> 4;
    constexpr int KW = NCH*32;

    bfrag bhw[4][NCH], blw[4][NCH];
#pragma unroll
    for (int g = 0; g < 4; ++g)
#pragma unroll
        for (int ch = 0; ch < NCH; ++ch) {
            size_t o = (size_t)((g*4 + w)*16 + fr)*KW + ch*32 + fc*8;
            bhw[g][ch] = *(const bfrag*)(Wthi + o);
            blw[g][ch] = *(const bfrag*)(Wtlo + o);
        }
    const int k = w*16 + fr;
    float bs[4], wx0[4], wx1[4];
#pragma unroll
    for (int g = 0; g < 4; ++g) {
        bs[g] = bias[g*64 + k];
        if (XEP) { wx0[g] = Wx[g*64 + k]; wx1[g] = Wx[256 + g*64 + k]; }
    }
    int colb[NCH];
#pragma unroll
    for (int ch = 0; ch < NCH; ++ch)
        colb[ch] = (NCH == 2 || ch < 2) ? (2048 + b*64 + ch*32)
                                        : (b*64 + (ch-2)*32);
    const int cc = lane >> 4;
    const size_t crow = (size_t)(b*64 + k)*NN;

    for (int nt = 0; nt < 8; ++nt) {
        const int n0 = n0blk + nt*16;
        bfrag ah[NCH], al[NCH];
#pragma unroll
        for (int ch = 0; ch < NCH; ++ch) {
            const unsigned int* ap = P + (size_t)(n0 + fr)*PW + colb[ch] + fc*8;
            uint4 u0 = *(const uint4*)ap;
            uint4 u1 = *(const uint4*)(ap + 4);
            unsigned int uu[8] = {u0.x,u0.y,u0.z,u0.w,u1.x,u1.y,u1.z,u1.w};
#pragma unroll
            for (int i = 0; i < 8; ++i) {
                ah[ch][i] = (short)(uu[i] & 0xffffu);
                al[ch][i] = (short)(uu[i] >> 16);
            }
        }
        f32x4 acc[4];
#pragma unroll
        for (int g = 0; g < 4; ++g)
#pragma unroll
            for (int r = 0; r < 4; ++r) acc[g][r] = 0.f;
#pragma unroll
        for (int ch = 0; ch < NCH; ++ch)
#pragma unroll
            for (int g = 0; g < 4; ++g) {
                acc[g] = __builtin_amdgcn_mfma_f32_16x16x32_bf16(ah[ch], bhw[g][ch], acc[g], 0, 0, 0);
                acc[g] = __builtin_amdgcn_mfma_f32_16x16x32_bf16(ah[ch], blw[g][ch], acc[g], 0, 0, 0);
                acc[g] = __builtin_amdgcn_mfma_f32_16x16x32_bf16(al[ch], bhw[g][ch], acc[g], 0, 0, 0);
            }
        const int nb = n0 + cc*4;
        float4 cold = *(const float4*)(cbuf + crow + nb);
        float xa0[4], xa1[4];
        if (XEP) {
#pragma unroll
            for (int r = 0; r < 4; ++r) {
                float2 cx = *(const float2*)(convX + (size_t)(nb + r)*XC + tstep*64 + b*2);
                xa0[r] = cx.x; xa1[r] = cx.y;
            }
        }
        float cn[4], hv[4];
#pragma unroll
        for (int r = 0; r < 4; ++r) {
            float pg[4];
#pragma unroll
            for (int g = 0; g < 4; ++g) {
                pg[g] = acc[g][r] + bs[g];
                if (XEP) pg[g] += xa0[r]*wx0[g] + xa1[r]*wx1[g];
            }
            float gi = fsig(pg[0]);
            float gf = fsig(pg[1]);
            float gg = ftanh(pg[2]);
            float go = fsig(pg[3]);
            float co = (&cold.x)[r];
            cn[r] = gf*co + gi*gg;
            hv[r] = go * ftanh(cn[r]);
        }
        *(float4*)(cbuf + crow + nb) = make_float4(cn[0], cn[1], cn[2], cn[3]);
        short hh[4], hl[4];
#pragma unroll
        for (int r = 0; r < 4; ++r) {
            hh[r] = f2bf(hv[r]);
            hl[r] = f2bf(hv[r] - bf2f(hh[r]));
        }
        *(short4*)(bhi + crow + nb) = make_short4(hh[0], hh[1], hh[2], hh[3]);
        *(short4*)(blo + crow + nb) = make_short4(hl[0], hl[1], hl[2], hl[3]);
    }
}

template<int NCH, bool XEP>
__global__ __launch_bounds__(256, 2) void cell_mfma(
        const unsigned int* __restrict__ P,
        const float* __restrict__ convX,
        const float* __restrict__ Wx,
        const short* __restrict__ Wthi, const short* __restrict__ Wtlo,
        const float* __restrict__ bias,
        float* __restrict__ cbuf,
        short* __restrict__ bhi, short* __restrict__ blo,
        int tstep) {
    cell_body<NCH, XEP>(P, convX, Wx, Wthi, Wtlo, bias, cbuf, bhi, blo,
                        tstep, blockIdx.x*128, blockIdx.y);
}

// fused: z=0 -> layer-2 cell at t; z=1 -> layer-1 cell at t+1 (independent)
__global__ __launch_bounds__(256, 2) void cell_fused(
        const unsigned int* __restrict__ P,
        const float* __restrict__ convX,
        const float* __restrict__ Wx1,
        const short* __restrict__ Wt2hi, const short* __restrict__ Wt2lo,
        const short* __restrict__ Wt1hi, const short* __restrict__ Wt1lo,
        const float* __restrict__ b2v, const float* __restrict__ b1v,
        float* __restrict__ cs2, float* __restrict__ cs1,
        short* __restrict__ Bhi, short* __restrict__ Blo,
        int tnext) {
    if (blockIdx.z == 0)
        cell_body<4, false>(P, nullptr, nullptr, Wt2hi, Wt2lo, b2v, cs2,
                            Bhi, Blo, 0, blockIdx.x*128, blockIdx.y);
    else
        cell_body<2, true>(P, convX, Wx1, Wt1hi, Wt1lo, b1v, cs1,
                           Bhi + HOFF, Blo + HOFF, tnext, blockIdx.x*128, blockIdx.y);
}

// ---------------- out = h2 @ Wp + bp -> [B,HOR,N,1] ----------------
__global__ __launch_bounds__(256) void proj_T(const short* __restrict__ Bhi,
        const short* __restrict__ Blo, const float* __restrict__ Wp,
        const float* __restrict__ bp, float* __restrict__ out) {
    __shared__ float sW[HH*HOR];
    __shared__ float sb[HOR];
    for (int i = threadIdx.x; i < HH*HOR; i += 256) sW[i] = Wp[i];
    if (threadIdx.x < HOR) sb[threadIdx.x] = bp[threadIdx.x];
    __syncthreads();
    int idx = blockIdx.x*256 + threadIdx.x;    // b*2048 + n
    int b = idx >> 11, n = idx & (NN-1);
    float acc[HOR];
#pragma unroll
    for (int j = 0; j < HOR; ++j) acc[j] = sb[j];
    for (int k = 0; k < HH; ++k) {
        size_t row = (size_t)(b*64 + k)*NN + n;
        float h = bf2f(Bhi[row]) + bf2f(Blo[row]);
#pragma unroll
        for (int j = 0; j < HOR; ++j) acc[j] = fmaf(h, sW[k*HOR + j], acc[j]);
    }
#pragma unroll
    for (int j = 0; j < HOR; ++j)
        out[(size_t)(b*HOR + j)*NN + n] = acc[j];
}

extern "C" void kernel_launch(void* const* d_in, const int* in_sizes, int n_in,
                              void* d_out, int out_size, void* d_ws, size_t ws_size,
                              hipStream_t stream) {
    const float* x  = (const float*)d_in[0];
    const float* E  = (const float*)d_in[1];
    const float* W1 = (const float*)d_in[2];
    const float* b1 = (const float*)d_in[3];
    const float* W2 = (const float*)d_in[4];
    const float* b2 = (const float*)d_in[5];
    const float* Wp = (const float*)d_in[6];
    const float* bp = (const float*)d_in[7];
    float* out = (float*)d_out;

    char* base = (char*)d_ws;
    short* Ahi    = (short*)base; base += (size_t)NN*NN*2;      // 8.4M
    short* Alo    = (short*)base; base += (size_t)NN*NN*2;      // 8.4M
    float* convX  = (float*)base; base += (size_t)NN*XC*4;      // 12.6M
    unsigned int* P = (unsigned int*)base; base += (size_t)NN*PW*4;  // 33.6M
    short* Bhi    = (short*)base; base += (size_t)2*NN*NN*2;    // 16.8M (h2|h1)
    short* Blo    = (short*)base; base += (size_t)2*NN*NN*2;    // 16.8M
    float* cs1    = (float*)base; base += (size_t)NN*NN*4;      // 16.8M
    float* cs2    = (float*)base; base += (size_t)NN*NN*4;      // 16.8M
    short* Wt2hi  = (short*)base; base += 256*128*2;
    short* Wt2lo  = (short*)base; base += 256*128*2;
    short* Wt1hi  = (short*)base; base += 256*64*2;
    short* Wt1lo  = (short*)base; base += 256*64*2;
    // XallT aliases P (consumed by convX GEMM before P is zeroed)
    short* XThi = (short*)P;
    short* XTlo = XThi + (size_t)XC*NN;

    hipMemsetAsync(cs1, 0, (size_t)NN*NN*4, stream);
    hipMemsetAsync(cs2, 0, (size_t)NN*NN*4, stream);

    compute_A_kernel<<<NN, 256, 0, stream>>>(E, Ahi, Alo);
    wsplit_T<<<(256*128 + 255)/256, 256, 0, stream>>>(W2, 0, 128, Wt2hi, Wt2lo);
    wsplit_T<<<(256*64 + 255)/256, 256, 0, stream>>>(W1, 2, 64, Wt1hi, Wt1lo);
    scatter_xall<<<(XC*NN)/256, 256, 0, stream>>>(x, XThi, XTlo);
    // convX = A @ Xall (once, all timesteps, f32)
    gc3_gemm<<<dim3(XC/128, NN/64), 256, 0, stream>>>(
        Ahi, Alo, XThi, XTlo, convX, XC);
    // XT region dead -> zero packed P for first-step reads
    hipMemsetAsync(P, 0, (size_t)NN*PW*4, stream);

    // cell1(0): reads P1=0 + convX(t=0) -> h1 rows of Bhi/Blo
    cell_mfma<2, true><<<dim3(NN/128, BB), 256, 0, stream>>>(
        P, convX, W1, Wt1hi, Wt1lo, b1, cs1, Bhi + HOFF, Blo + HOFF, 0);
    // P1(0) = A @ h1(0)  (cols [2048,4096) only)
    gcsplit<<<dim3(8, 16), 512, 0, stream>>>(Ahi, Alo, Bhi, Blo, P, 2048);

    for (int t = 0; t < TT; ++t) {
        if (t < TT-1) {
            // cell2(t) + cell1(t+1) fused (both read P1(t); independent)
            cell_fused<<<dim3(NN/128, BB, 2), 256, 0, stream>>>(
                P, convX, W1, Wt2hi, Wt2lo, Wt1hi, Wt1lo, b2, b1,
                cs2, cs1, Bhi, Blo, t+1);
            // merged GEMM: [P2(t) | P1(t+1)] = A @ [h2(t) | h1(t+1)]
            gcsplit<<<dim3(16, 16), 512, 0, stream>>>(Ahi, Alo, Bhi, Blo, P, 0);
        } else {
            // final step: only cell2(23)
            cell_mfma<4, false><<<dim3(NN/128, BB), 256, 0, stream>>>(
                P, nullptr, nullptr, Wt2hi, Wt2lo, b2, cs2, Bhi, Blo, 0);
        }
    }
    proj_T<<<(BB*NN)/256, 256, 0, stream>>>(Bhi, Blo, Wp, bp, out);
}

// Round 13
// 3456.245 us; speedup vs baseline: 1.0777x; 1.0777x over previous
//
#include <hip/hip_runtime.h>
#include <hip/hip_bf16.h>
#include <cstddef>
#include <cstdint>

#define NN   2048
#define BB   32
#define TT   24
#define CIN  2
#define HH   64
#define EMBD 16
#define HOR  12
#define XC   (TT*BB*CIN)   // 1536 cols of precomputed A@x
#define PW   4096          // P row width: cols [0,2048)=P2, [2048,4096)=P1
#define NT2  64            // K-tiles of 32 (K=2048)
#define HOFF ((size_t)2048*NN)   // h1 row offset in Bhi/Blo

using bfrag  = __attribute__((ext_vector_type(8))) short;   // 8 bf16 = 4 VGPR
using f32x4  = __attribute__((ext_vector_type(4))) float;

static __device__ __forceinline__ short f2bf(float f) {
    __hip_bfloat16 h = __float2bfloat16(f);
    return *reinterpret_cast<short*>(&h);
}
static __device__ __forceinline__ float bf2f(short s) {
    __hip_bfloat16 h;
    *reinterpret_cast<short*>(&h) = s;
    return __bfloat162float(h);
}
static __device__ __forceinline__ unsigned int packsplit(float v) {
    short hb = f2bf(v);
    short lb = f2bf(v - bf2f(hb));
    return (unsigned int)(unsigned short)hb | ((unsigned int)(unsigned short)lb << 16);
}
// fast transcendentals: v_exp_f32 + v_rcp_f32; saturate correctly, no NaN
static __device__ __forceinline__ float fsig(float x) {
    return __builtin_amdgcn_rcpf(1.f + __expf(-x));
}
static __device__ __forceinline__ float ftanh(float x) {
    return 1.f - 2.f*__builtin_amdgcn_rcpf(1.f + __expf(2.f*x));
}

#define AS1 __attribute__((address_space(1)))
#define AS3 __attribute__((address_space(3)))
static __device__ __forceinline__ void gload16(const short* g, short* l) {
    __builtin_amdgcn_global_load_lds((const AS1 void*)g, (AS3 void*)l, 16, 0, 0);
}

// ---------- A = softmax(relu(E E^T)) -> split bf16 hi/lo ----------
__global__ __launch_bounds__(256) void compute_A_kernel(const float* __restrict__ E,
                                                        short* __restrict__ Ahi,
                                                        short* __restrict__ Alo) {
    __shared__ float srow[NN];
    __shared__ float sred[256];
    int row = blockIdx.x;
    float er[EMBD];
#pragma unroll
    for (int k = 0; k < EMBD; ++k) er[k] = E[row*EMBD + k];
    float lmax = -1e30f;
    for (int j = threadIdx.x; j < NN; j += 256) {
        const float* ej = E + j*EMBD;
        float d = 0.f;
#pragma unroll
        for (int k = 0; k < EMBD; ++k) d = fmaf(er[k], ej[k], d);
        d = fmaxf(d, 0.f);
        srow[j] = d;
        lmax = fmaxf(lmax, d);
    }
    sred[threadIdx.x] = lmax;
    __syncthreads();
    for (int s = 128; s > 0; s >>= 1) {
        if (threadIdx.x < s) sred[threadIdx.x] = fmaxf(sred[threadIdx.x], sred[threadIdx.x+s]);
        __syncthreads();
    }
    float rmax = sred[0];
    __syncthreads();
    float lsum = 0.f;
    for (int j = threadIdx.x; j < NN; j += 256) {
        float e = expf(srow[j] - rmax);
        srow[j] = e;
        lsum += e;
    }
    sred[threadIdx.x] = lsum;
    __syncthreads();
    for (int s = 128; s > 0; s >>= 1) {
        if (threadIdx.x < s) sred[threadIdx.x] += sred[threadIdx.x+s];
        __syncthreads();
    }
    float rinv = 1.f / sred[0];
    for (int j = threadIdx.x; j < NN; j += 256) {
        float v = srow[j] * rinv;
        short h = f2bf(v);
        Ahi[(size_t)row*NN + j] = h;
        Alo[(size_t)row*NN + j] = f2bf(v - bf2f(h));
    }
}

// ---------------- build XallT hi/lo: [col=(t*32+b)*2+c][n] ----------------
__global__ void scatter_xall(const float* __restrict__ x,
                             short* __restrict__ hi, short* __restrict__ lo) {
    int idx = blockIdx.x*256 + threadIdx.x;     // col*2048 + n
    int n = idx & (NN-1);
    int col = idx >> 11;
    int c = col & 1, b = (col >> 1) & 31, t = col >> 6;
    float v = x[(size_t)(((size_t)b*TT + t)*NN + n)*CIN + c];
    short h = f2bf(v);
    size_t o = (size_t)col*NN + n;
    hi[o] = h;
    lo[o] = f2bf(v - bf2f(h));
}

// ---------------- W^T split: Wt[j][c] = split(W[rowoff+c][j]) ----------------
__global__ void wsplit_T(const float* __restrict__ W, int rowoff, int Kd,
                         short* __restrict__ hi, short* __restrict__ lo) {
    int id = blockIdx.x*256 + threadIdx.x;      // j*Kd + c
    if (id >= 256*Kd) return;
    int j = id / Kd, c = id - j*Kd;
    float v = W[(size_t)(rowoff + c)*256 + j];
    short h = f2bf(v);
    hi[id] = h;
    lo[id] = f2bf(v - bf2f(h));
}

// ---------------- convX GEMM: f32 out (proven kernel) --------------
__global__ __launch_bounds__(256, 3) void gc3_gemm(
        const short* __restrict__ Ahi, const short* __restrict__ Alo,
        const short* __restrict__ Bhi, const short* __restrict__ Blo,
        float* __restrict__ Cout, int outStride) {
    __shared__ short As[12288];
    short* AsHi = As;
    short* AsLo = As + 2048;
    short* BsHi = As + 4096;
    short* BsLo = As + 8192;
    const int t = threadIdx.x;
    const int w = t >> 6, lane = t & 63;
    const int wm = w >> 1, wn = w & 1;
    const int fr = lane & 15, fc = lane >> 4;
    const int rowbase = blockIdx.y * 64;
    const int colbase = blockIdx.x * 128;

    const int rp = t >> 3, ql = t & 7;
    const int qs = ql ^ (rp & 7);
    const int srow = rp*2 + (qs >> 2);
    const int sch  = (qs & 3) * 8;
    const short* aHiS = Ahi + (size_t)(rowbase + srow)*NN + sch;
    const short* aLoS = Alo + (size_t)(rowbase + srow)*NN + sch;
    const short* bHiS = Bhi + (size_t)(colbase + srow)*NN + sch;
    const short* bLoS = Blo + (size_t)(colbase + srow)*NN + sch;
    const size_t bHalf = (size_t)64*NN;

    short* aHiD  = AsHi + t*8;
    short* aLoD  = AsLo + t*8;
    short* bHiD0 = BsHi + t*8;
    short* bHiD1 = BsHi + 2048 + t*8;
    short* bLoD0 = BsLo + t*8;
    short* bLoD1 = BsLo + 2048 + t*8;

    auto ldsoff0 = [](int row, int f) {
        int rr = row >> 1;
        int q = (((row & 1) << 2) | f) ^ (rr & 7);
        return rr*64 + q*8;
    };
    int aoff[2], boff[4];
#pragma unroll
    for (int m = 0; m < 2; ++m) aoff[m] = ldsoff0(wm*32 + m*16 + fr, fc);
#pragma unroll
    for (int n = 0; n < 4; ++n) boff[n] = ldsoff0(wn*64 + n*16 + fr, fc);

    f32x4 acc[2][4];
#pragma unroll
    for (int m = 0; m < 2; ++m)
#pragma unroll
        for (int n = 0; n < 4; ++n)
#pragma unroll
            for (int r = 0; r < 4; ++r) acc[m][n][r] = 0.f;

    for (int k0 = 0; k0 < NN; k0 += 32) {
        gload16(aHiS, aHiD);
        gload16(aLoS, aLoD);
        gload16(bHiS, bHiD0);
        gload16(bHiS + bHalf, bHiD1);
        gload16(bLoS, bLoD0);
        gload16(bLoS + bHalf, bLoD1);
        aHiS += 32; aLoS += 32; bHiS += 32; bLoS += 32;
        __syncthreads();
        bfrag ah[2], al[2], bh[4], bl[4];
#pragma unroll
        for (int m = 0; m < 2; ++m) {
            ah[m] = *(const bfrag*)(AsHi + aoff[m]);
            al[m] = *(const bfrag*)(AsLo + aoff[m]);
        }
#pragma unroll
        for (int n = 0; n < 4; ++n) {
            bh[n] = *(const bfrag*)(BsHi + boff[n]);
            bl[n] = *(const bfrag*)(BsLo + boff[n]);
        }
#pragma unroll
        for (int m = 0; m < 2; ++m)
#pragma unroll
            for (int n = 0; n < 4; ++n) {
                acc[m][n] = __builtin_amdgcn_mfma_f32_16x16x32_bf16(ah[m], bh[n], acc[m][n], 0, 0, 0);
                acc[m][n] = __builtin_amdgcn_mfma_f32_16x16x32_bf16(ah[m], bl[n], acc[m][n], 0, 0, 0);
                acc[m][n] = __builtin_amdgcn_mfma_f32_16x16x32_bf16(al[m], bh[n], acc[m][n], 0, 0, 0);
            }
        __syncthreads();
    }
#pragma unroll
    for (int m = 0; m < 2; ++m) {
        const int gr = rowbase + wm*32 + m*16 + fc*4;
#pragma unroll
        for (int n = 0; n < 4; ++n) {
            const int gc = colbase + wn*64 + n*16 + fr;
#pragma unroll
            for (int r = 0; r < 4; ++r)
                Cout[(size_t)(gr + r)*outStride + gc] = acc[m][n][r];
        }
    }
}

// ------- recurrent GEMM: split 3-term, K=2048, BK=32, 16x16x32 frags ---------
// C[2048][PW] packed = (Ah+Al) @ (Bh+Bl)^T (3 terms, Al*Bl dropped)
// 128x256 tile, 8 waves (2Mx4N), 3-deep LDS (144KB), vmcnt(6) counted, 1 barrier.
// LDS: 128-BYTE rows, hi/lo interleaved (chunks 0-3 = hi, 4-7 = lo), chunk
// swizzle c ^= row&7. FRAGMENT SHAPE = 16x16x32 (fr=lane&15, fc=lane>>4):
// the 16-row x 4-chunk lane map is the ONLY pattern measured conflict-free
// (gemm8p/gc3 = 0); all 32-row (32x32-frag) variants measured a swizzle-
// invariant 4cy/read (rounds 9-12).
__global__ __launch_bounds__(512, 2) void gcsplit(
        const short* __restrict__ Ahi, const short* __restrict__ Alo,
        const short* __restrict__ Bhi, const short* __restrict__ Blo,
        unsigned int* __restrict__ Cpk, int colstart) {
    __shared__ short lds[3*24576];
    const int tid = threadIdx.x;
    const int w = tid >> 6, lane = tid & 63;
    const int wm = w >> 2, wn = w & 3;
    const int fr = lane & 15, fc = lane >> 4;
    // bijective XCD swizzle (grid counts divisible by 8)
    const int gx = gridDim.x;
    const int nwg = gx * gridDim.y;
    const int fid = blockIdx.y * gx + blockIdx.x;
    const int swz = (fid & 7) * (nwg >> 3) + (fid >> 3);
    const int rowbase = (swz / gx) * 128;
    const int colbase = colstart + (swz % gx) * 256;

    // staging decode: thread -> (row = s*64 + tid>>3, c' = tid&7),
    // source chunk c = c' ^ (row&7); c<4 -> hi plane col c, else lo plane col c-4.
    const int trow = tid >> 3;
    const int ca = (tid & 7) ^ (trow & 7);
    const short* aplane = (ca < 4) ? Ahi : Alo;
    const short* bplane = (ca < 4) ? Bhi : Blo;
    const int ccol = (ca & 3) * 8;
    const short* aS0 = aplane + (size_t)(rowbase + trow)*NN + ccol;
    const short* aS1 = aplane + (size_t)(rowbase + 64 + trow)*NN + ccol;
    const short* bS0 = bplane + (size_t)(colbase + trow)*NN + ccol;
    const short* bS1 = bplane + (size_t)(colbase + 64 + trow)*NN + ccol;
    const short* bS2 = bplane + (size_t)(colbase + 128 + trow)*NN + ccol;
    const short* bS3 = bplane + (size_t)(colbase + 192 + trow)*NN + ccol;

    // fragment read offsets (shorts): row*64 + (c ^ (row&7))*8, c in 0..7
    auto ldsoff = [](int row, int c) {
        return row*64 + (c ^ (row & 7))*8;
    };
    int aoffH[4], aoffL[4], boffH[4], boffL[4];
#pragma unroll
    for (int m = 0; m < 4; ++m) {
        int row = wm*64 + m*16 + fr;
        aoffH[m] = ldsoff(row, fc);
        aoffL[m] = ldsoff(row, 4 + fc);
    }
#pragma unroll
    for (int n = 0; n < 4; ++n) {
        int row = wn*64 + n*16 + fr;
        boffH[n] = 8192 + ldsoff(row, fc);
        boffL[n] = 8192 + ldsoff(row, 4 + fc);
    }

    f32x4 acc[4][4];
#pragma unroll
    for (int m = 0; m < 4; ++m)
#pragma unroll
        for (int n = 0; n < 4; ++n)
#pragma unroll
            for (int r = 0; r < 4; ++r) acc[m][n][r] = 0.f;

    short* bC = lds;             // compute buffer (tile t)
    short* bN = lds + 24576;     // tile t+1
    short* bP = lds + 49152;     // prefetch dest (tile t+2)

    auto STAGE = [&](short* dst, int koff) {
        gload16(aS0 + koff, dst + tid*8);
        gload16(aS1 + koff, dst + 4096  + tid*8);
        gload16(bS0 + koff, dst + 8192  + tid*8);
        gload16(bS1 + koff, dst + 12288 + tid*8);
        gload16(bS2 + koff, dst + 16384 + tid*8);
        gload16(bS3 + koff, dst + 20480 + tid*8);
    };
    // prologue: stage tiles 0 and 1
    STAGE(bC, 0);
    STAGE(bN, 32);

    for (int t = 0; t < NT2; ++t) {
        // wait: tile t's 6 loads done (tile t+1's 6 may remain in flight)
        if (t < NT2-1) { asm volatile("s_waitcnt vmcnt(6)" ::: "memory"); }
        else           { asm volatile("s_waitcnt vmcnt(0)" ::: "memory"); }
        __builtin_amdgcn_s_barrier();     // buf bC ready; bP free
        if (t + 2 < NT2) STAGE(bP, (t + 2) * 32);
        __builtin_amdgcn_sched_barrier(0);   // pin stage-issue before compute
        // issue ALL 16 reads first (hi operands first); fine-grained lgkmcnt
        // lets tail reads land under the first MFMA cluster
        bfrag ah[4], al[4], bh[4], bl[4];
#pragma unroll
        for (int m = 0; m < 4; ++m) ah[m] = *(const bfrag*)(bC + aoffH[m]);
#pragma unroll
        for (int n = 0; n < 4; ++n) bh[n] = *(const bfrag*)(bC + boffH[n]);
#pragma unroll
        for (int m = 0; m < 4; ++m) al[m] = *(const bfrag*)(bC + aoffL[m]);
#pragma unroll
        for (int n = 0; n < 4; ++n) bl[n] = *(const bfrag*)(bC + boffL[n]);
        __builtin_amdgcn_s_setprio(1);
#pragma unroll
        for (int m = 0; m < 4; ++m)
#pragma unroll
            for (int n = 0; n < 4; ++n)
                acc[m][n] = __builtin_amdgcn_mfma_f32_16x16x32_bf16(
                    ah[m], bh[n], acc[m][n], 0, 0, 0);
#pragma unroll
        for (int m = 0; m < 4; ++m)
#pragma unroll
            for (int n = 0; n < 4; ++n) {
                acc[m][n] = __builtin_amdgcn_mfma_f32_16x16x32_bf16(
                    ah[m], bl[n], acc[m][n], 0, 0, 0);
                acc[m][n] = __builtin_amdgcn_mfma_f32_16x16x32_bf16(
                    al[m], bh[n], acc[m][n], 0, 0, 0);
            }
        __builtin_amdgcn_s_setprio(0);
        // rotate buffers
        short* tmp = bC; bC = bN; bN = bP; bP = tmp;
    }
    // epilogue: C/D (16x16): col = lane&15, row = (lane>>4)*4 + r
#pragma unroll
    for (int m = 0; m < 4; ++m) {
        const int gr0 = rowbase + wm*64 + m*16 + fc*4;
#pragma unroll
        for (int n = 0; n < 4; ++n) {
            const int gc = colbase + wn*64 + n*16 + fr;
#pragma unroll
            for (int r = 0; r < 4; ++r)
                Cpk[(size_t)(gr0 + r)*PW + gc] = packsplit(acc[m][n][r]);
        }
    }
}

// ---------------- MFMA LSTM cell body (shared device fn) ----------------
// P packed (hi|lo). h written to Bhi/Blo rows (b*64+k), stride NN.
template<int NCH, bool XEP>
static __device__ __forceinline__ void cell_body(
        const unsigned int* __restrict__ P,
        const float* __restrict__ convX,
        const float* __restrict__ Wx,
        const short* __restrict__ Wthi, const short* __restrict__ Wtlo,
        const float* __restrict__ bias,
        float* __restrict__ cbuf,
        short* __restrict__ bhi, short* __restrict__ blo,
        int tstep, int n0blk, int b) {
    const int t = threadIdx.x;
    const int w = t >> 6, lane = t & 63;
    const int fr = lane & 15, fc = lane >> 4;
    constexpr int KW = NCH*32;

    bfrag bhw[4][NCH], blw[4][NCH];
#pragma unroll
    for (int g = 0; g < 4; ++g)
#pragma unroll
        for (int ch = 0; ch < NCH; ++ch) {
            size_t o = (size_t)((g*4 + w)*16 + fr)*KW + ch*32 + fc*8;
            bhw[g][ch] = *(const bfrag*)(Wthi + o);
            blw[g][ch] = *(const bfrag*)(Wtlo + o);
        }
    const int k = w*16 + fr;
    float bs[4], wx0[4], wx1[4];
#pragma unroll
    for (int g = 0; g < 4; ++g) {
        bs[g] = bias[g*64 + k];
        if (XEP) { wx0[g] = Wx[g*64 + k]; wx1[g] = Wx[256 + g*64 + k]; }
    }
    int colb[NCH];
#pragma unroll
    for (int ch = 0; ch < NCH; ++ch)
        colb[ch] = (NCH == 2 || ch < 2) ? (2048 + b*64 + ch*32)
                                        : (b*64 + (ch-2)*32);
    const int cc = lane >> 4;
    const size_t crow = (size_t)(b*64 + k)*NN;

    for (int nt = 0; nt < 8; ++nt) {
        const int n0 = n0blk + nt*16;
        bfrag ah[NCH], al[NCH];
#pragma unroll
        for (int ch = 0; ch < NCH; ++ch) {
            const unsigned int* ap = P + (size_t)(n0 + fr)*PW + colb[ch] + fc*8;
            uint4 u0 = *(const uint4*)ap;
            uint4 u1 = *(const uint4*)(ap + 4);
            unsigned int uu[8] = {u0.x,u0.y,u0.z,u0.w,u1.x,u1.y,u1.z,u1.w};
#pragma unroll
            for (int i = 0; i < 8; ++i) {
                ah[ch][i] = (short)(uu[i] & 0xffffu);
                al[ch][i] = (short)(uu[i] >> 16);
            }
        }
        f32x4 acc[4];
#pragma unroll
        for (int g = 0; g < 4; ++g)
#pragma unroll
            for (int r = 0; r < 4; ++r) acc[g][r] = 0.f;
#pragma unroll
        for (int ch = 0; ch < NCH; ++ch)
#pragma unroll
            for (int g = 0; g < 4; ++g) {
                acc[g] = __builtin_amdgcn_mfma_f32_16x16x32_bf16(ah[ch], bhw[g][ch], acc[g], 0, 0, 0);
                acc[g] = __builtin_amdgcn_mfma_f32_16x16x32_bf16(ah[ch], blw[g][ch], acc[g], 0, 0, 0);
                acc[g] = __builtin_amdgcn_mfma_f32_16x16x32_bf16(al[ch], bhw[g][ch], acc[g], 0, 0, 0);
            }
        const int nb = n0 + cc*4;
        float4 cold = *(const float4*)(cbuf + crow + nb);
        float xa0[4], xa1[4];
        if (XEP) {
#pragma unroll
            for (int r = 0; r < 4; ++r) {
                float2 cx = *(const float2*)(convX + (size_t)(nb + r)*XC + tstep*64 + b*2);
                xa0[r] = cx.x; xa1[r] = cx.y;
            }
        }
        float cn[4], hv[4];
#pragma unroll
        for (int r = 0; r < 4; ++r) {
            float pg[4];
#pragma unroll
            for (int g = 0; g < 4; ++g) {
                pg[g] = acc[g][r] + bs[g];
                if (XEP) pg[g] += xa0[r]*wx0[g] + xa1[r]*wx1[g];
            }
            float gi = fsig(pg[0]);
            float gf = fsig(pg[1]);
            float gg = ftanh(pg[2]);
            float go = fsig(pg[3]);
            float co = (&cold.x)[r];
            cn[r] = gf*co + gi*gg;
            hv[r] = go * ftanh(cn[r]);
        }
        *(float4*)(cbuf + crow + nb) = make_float4(cn[0], cn[1], cn[2], cn[3]);
        short hh[4], hl[4];
#pragma unroll
        for (int r = 0; r < 4; ++r) {
            hh[r] = f2bf(hv[r]);
            hl[r] = f2bf(hv[r] - bf2f(hh[r]));
        }
        *(short4*)(bhi + crow + nb) = make_short4(hh[0], hh[1], hh[2], hh[3]);
        *(short4*)(blo + crow + nb) = make_short4(hl[0], hl[1], hl[2], hl[3]);
    }
}

template<int NCH, bool XEP>
__global__ __launch_bounds__(256, 2) void cell_mfma(
        const unsigned int* __restrict__ P,
        const float* __restrict__ convX,
        const float* __restrict__ Wx,
        const short* __restrict__ Wthi, const short* __restrict__ Wtlo,
        const float* __restrict__ bias,
        float* __restrict__ cbuf,
        short* __restrict__ bhi, short* __restrict__ blo,
        int tstep) {
    cell_body<NCH, XEP>(P, convX, Wx, Wthi, Wtlo, bias, cbuf, bhi, blo,
                        tstep, blockIdx.x*128, blockIdx.y);
}

// fused: z=0 -> layer-2 cell at t; z=1 -> layer-1 cell at t+1 (independent)
__global__ __launch_bounds__(256, 2) void cell_fused(
        const unsigned int* __restrict__ P,
        const float* __restrict__ convX,
        const float* __restrict__ Wx1,
        const short* __restrict__ Wt2hi, const short* __restrict__ Wt2lo,
        const short* __restrict__ Wt1hi, const short* __restrict__ Wt1lo,
        const float* __restrict__ b2v, const float* __restrict__ b1v,
        float* __restrict__ cs2, float* __restrict__ cs1,
        short* __restrict__ Bhi, short* __restrict__ Blo,
        int tnext) {
    if (blockIdx.z == 0)
        cell_body<4, false>(P, nullptr, nullptr, Wt2hi, Wt2lo, b2v, cs2,
                            Bhi, Blo, 0, blockIdx.x*128, blockIdx.y);
    else
        cell_body<2, true>(P, convX, Wx1, Wt1hi, Wt1lo, b1v, cs1,
                           Bhi + HOFF, Blo + HOFF, tnext, blockIdx.x*128, blockIdx.y);
}

// ---------------- out = h2 @ Wp + bp -> [B,HOR,N,1] ----------------
__global__ __launch_bounds__(256) void proj_T(const short* __restrict__ Bhi,
        const short* __restrict__ Blo, const float* __restrict__ Wp,
        const float* __restrict__ bp, float* __restrict__ out) {
    __shared__ float sW[HH*HOR];
    __shared__ float sb[HOR];
    for (int i = threadIdx.x; i < HH*HOR; i += 256) sW[i] = Wp[i];
    if (threadIdx.x < HOR) sb[threadIdx.x] = bp[threadIdx.x];
    __syncthreads();
    int idx = blockIdx.x*256 + threadIdx.x;    // b*2048 + n
    int b = idx >> 11, n = idx & (NN-1);
    float acc[HOR];
#pragma unroll
    for (int j = 0; j < HOR; ++j) acc[j] = sb[j];
    for (int k = 0; k < HH; ++k) {
        size_t row = (size_t)(b*64 + k)*NN + n;
        float h = bf2f(Bhi[row]) + bf2f(Blo[row]);
#pragma unroll
        for (int j = 0; j < HOR; ++j) acc[j] = fmaf(h, sW[k*HOR + j], acc[j]);
    }
#pragma unroll
    for (int j = 0; j < HOR; ++j)
        out[(size_t)(b*HOR + j)*NN + n] = acc[j];
}

extern "C" void kernel_launch(void* const* d_in, const int* in_sizes, int n_in,
                              void* d_out, int out_size, void* d_ws, size_t ws_size,
                              hipStream_t stream) {
    const float* x  = (const float*)d_in[0];
    const float* E  = (const float*)d_in[1];
    const float* W1 = (const float*)d_in[2];
    const float* b1 = (const float*)d_in[3];
    const float* W2 = (const float*)d_in[4];
    const float* b2 = (const float*)d_in[5];
    const float* Wp = (const float*)d_in[6];
    const float* bp = (const float*)d_in[7];
    float* out = (float*)d_out;

    char* base = (char*)d_ws;
    short* Ahi    = (short*)base; base += (size_t)NN*NN*2;      // 8.4M
    short* Alo    = (short*)base; base += (size_t)NN*NN*2;      // 8.4M
    float* convX  = (float*)base; base += (size_t)NN*XC*4;      // 12.6M
    unsigned int* P = (unsigned int*)base; base += (size_t)NN*PW*4;  // 33.6M
    short* Bhi    = (short*)base; base += (size_t)2*NN*NN*2;    // 16.8M (h2|h1)
    short* Blo    = (short*)base; base += (size_t)2*NN*NN*2;    // 16.8M
    float* cs1    = (float*)base; base += (size_t)NN*NN*4;      // 16.8M
    float* cs2    = (float*)base; base += (size_t)NN*NN*4;      // 16.8M
    short* Wt2hi  = (short*)base; base += 256*128*2;
    short* Wt2lo  = (short*)base; base += 256*128*2;
    short* Wt1hi  = (short*)base; base += 256*64*2;
    short* Wt1lo  = (short*)base; base += 256*64*2;
    // XallT aliases P (consumed by convX GEMM before P is zeroed)
    short* XThi = (short*)P;
    short* XTlo = XThi + (size_t)XC*NN;

    hipMemsetAsync(cs1, 0, (size_t)NN*NN*4, stream);
    hipMemsetAsync(cs2, 0, (size_t)NN*NN*4, stream);

    compute_A_kernel<<<NN, 256, 0, stream>>>(E, Ahi, Alo);
    wsplit_T<<<(256*128 + 255)/256, 256, 0, stream>>>(W2, 0, 128, Wt2hi, Wt2lo);
    wsplit_T<<<(256*64 + 255)/256, 256, 0, stream>>>(W1, 2, 64, Wt1hi, Wt1lo);
    scatter_xall<<<(XC*NN)/256, 256, 0, stream>>>(x, XThi, XTlo);
    // convX = A @ Xall (once, all timesteps, f32)
    gc3_gemm<<<dim3(XC/128, NN/64), 256, 0, stream>>>(
        Ahi, Alo, XThi, XTlo, convX, XC);
    // XT region dead -> zero packed P for first-step reads
    hipMemsetAsync(P, 0, (size_t)NN*PW*4, stream);

    // cell1(0): reads P1=0 + convX(t=0) -> h1 rows of Bhi/Blo
    cell_mfma<2, true><<<dim3(NN/128, BB), 256, 0, stream>>>(
        P, convX, W1, Wt1hi, Wt1lo, b1, cs1, Bhi + HOFF, Blo + HOFF, 0);
    // P1(0) = A @ h1(0)  (cols [2048,4096) only)
    gcsplit<<<dim3(8, 16), 512, 0, stream>>>(Ahi, Alo, Bhi, Blo, P, 2048);

    for (int t = 0; t < TT; ++t) {
        if (t < TT-1) {
            // cell2(t) + cell1(t+1) fused (both read P1(t); independent)
            cell_fused<<<dim3(NN/128, BB, 2), 256, 0, stream>>>(
                P, convX, W1, Wt2hi, Wt2lo, Wt1hi, Wt1lo, b2, b1,
                cs2, cs1, Bhi, Blo, t+1);
            // merged GEMM: [P2(t) | P1(t+1)] = A @ [h2(t) | h1(t+1)]
            gcsplit<<<dim3(16, 16), 512, 0, stream>>>(Ahi, Alo, Bhi, Blo, P, 0);
        } else {
            // final step: only cell2(23)
            cell_mfma<4, false><<<dim3(NN/128, BB), 256, 0, stream>>>(
                P, nullptr, nullptr, Wt2hi, Wt2lo, b2, cs2, Bhi, Blo, 0);
        }
    }
    proj_T<<<(BB*NN)/256, 256, 0, stream>>>(Bhi, Blo, Wp, bp, out);
}